// Round 4
// baseline (562.479 us; speedup 1.0000x reference)
//
#include <hip/hip_runtime.h>

// ---------------------------------------------------------------------------
// CausalAttention: B=8, S=2048, D=1024, fp32 in, fp32 OUT (reference returns
// float32 — rounds 1-3 failed solely from storing bf16 into a float* d_out;
// all three pipelines produced identical absmax, validating the MFMA layouts
// and glds staging).
// Round 4: fp16 MFMA pipeline, glds staging for scores/PV, fp32 output.
//   ws (160 MB): Q 32 | K 32 | Vt 32 | Sc 64.
// ---------------------------------------------------------------------------

typedef _Float16 v8h __attribute__((ext_vector_type(8)));
typedef _Float16 v4h __attribute__((ext_vector_type(4)));
typedef float    v4f __attribute__((ext_vector_type(4)));

#define TM 128
#define TN 128
#define BK 64

__device__ __forceinline__ void async16(const _Float16* g, _Float16* l) {
  // global -> LDS direct copy, 16B/lane; LDS dest = wave-uniform base,
  // HW adds lane*16.  [validated: rounds 1-3 bit-agree]
  __builtin_amdgcn_global_load_lds(
      (__attribute__((address_space(1))) void*)(void*)g,
      (__attribute__((address_space(3))) void*)l, 16, 0, 0);
}

// MFMA core over one 128x64 LDS slab pair. A-frag lane: A[m=lane&15][k=quad*8+j].
__device__ __forceinline__ void mfma_slab(const _Float16* As, const _Float16* Bs,
                                          int wr, int wc, int lr, int quad,
                                          v4f acc[4][4]) {
#pragma unroll
  for (int ks = 0; ks < 2; ++ks) {
    v8h a[4], b[4];
#pragma unroll
    for (int i = 0; i < 4; ++i) {
      a[i] = *(const v8h*)&As[(wr + i * 16 + lr) * BK + ks * 32 + quad * 8];
      b[i] = *(const v8h*)&Bs[(wc + i * 16 + lr) * BK + ks * 32 + quad * 8];
    }
#pragma unroll
    for (int i = 0; i < 4; ++i)
#pragma unroll
      for (int j = 0; j < 4; ++j)
        acc[i][j] = __builtin_amdgcn_mfma_f32_16x16x32_f16(a[i], b[j],
                                                           acc[i][j], 0, 0, 0);
  }
}

// ---------------------------------------------------------------------------
// Projection: C[m][n] = X[m][:] . W[n][:], n in [0,3072) packed Q|K|V.
// fp32 converted to f16 in staging. Q,K stored [16384][1024]; V transposed
// to Vt[b][d][s].
// ---------------------------------------------------------------------------
__global__ __launch_bounds__(256)
void proj_gemm(const float* __restrict__ X, const float* __restrict__ Wq,
               const float* __restrict__ Wk, const float* __restrict__ Wv,
               _Float16* __restrict__ Qb, _Float16* __restrict__ Kb,
               _Float16* __restrict__ Vt) {
  const int tid = threadIdx.x;
  const int n0 = blockIdx.x * TN, m0 = blockIdx.y * TM;
  const int which = n0 >> 10;                    // 0=Q 1=K 2=V, block-uniform
  const float* Wbase = (which == 0) ? Wq : (which == 1) ? Wk : Wv;
  const int nw = n0 & 1023;

  __shared__ _Float16 As[TM * BK];
  __shared__ _Float16 Bs[TN * BK];

  const int lane = tid & 63, w = tid >> 6;
  const int wr = (w >> 1) * 64, wc = (w & 1) * 64;
  const int lr = lane & 15, quad = lane >> 4;

  v4f acc[4][4];
#pragma unroll
  for (int i = 0; i < 4; ++i)
#pragma unroll
    for (int j = 0; j < 4; ++j) acc[i][j] = (v4f){0.f, 0.f, 0.f, 0.f};

  for (int kt = 0; kt < 1024 / BK; ++kt) {
    const int k0 = kt * BK;
#pragma unroll
    for (int r = 0; r < 4; ++r) {
      const int c = r * 256 + tid;               // chunk id: 8 f16 elems
      const int row = c >> 3, col = (c & 7) * 8;
      {
        const float* p = X + (size_t)(m0 + row) * 1024 + k0 + col;
        float4 a0 = *(const float4*)p;
        float4 a1 = *(const float4*)(p + 4);
        v8h v = {(_Float16)a0.x, (_Float16)a0.y, (_Float16)a0.z, (_Float16)a0.w,
                 (_Float16)a1.x, (_Float16)a1.y, (_Float16)a1.z, (_Float16)a1.w};
        *(v8h*)&As[row * BK + col] = v;
      }
      {
        const float* p = Wbase + (size_t)(nw + row) * 1024 + k0 + col;
        float4 b0 = *(const float4*)p;
        float4 b1 = *(const float4*)(p + 4);
        v8h v = {(_Float16)b0.x, (_Float16)b0.y, (_Float16)b0.z, (_Float16)b0.w,
                 (_Float16)b1.x, (_Float16)b1.y, (_Float16)b1.z, (_Float16)b1.w};
        *(v8h*)&Bs[row * BK + col] = v;
      }
    }
    __syncthreads();
    mfma_slab(As, Bs, wr, wc, lr, quad, acc);
    __syncthreads();
  }

  // C/D layout: col = lane&15, row = quad*4 + reg  [m89, validated here]
#pragma unroll
  for (int i = 0; i < 4; ++i) {
    const int r0 = m0 + wr + i * 16 + quad * 4;
#pragma unroll
    for (int j = 0; j < 4; ++j) {
      const int cl = wc + j * 16 + lr;
      if (which < 2) {
        _Float16* dst = (which == 0) ? Qb : Kb;
        const int col = nw + cl;
#pragma unroll
        for (int rg = 0; rg < 4; ++rg)
          dst[(size_t)(r0 + rg) * 1024 + col] = (_Float16)acc[i][j][rg];
      } else {
        const int d = nw + cl;
        const int b = r0 >> 11, s = r0 & 2047;
        v4h o = {(_Float16)acc[i][j][0], (_Float16)acc[i][j][1],
                 (_Float16)acc[i][j][2], (_Float16)acc[i][j][3]};
        *(v4h*)(Vt + (size_t)b * 1024 * 2048 + (size_t)d * 2048 + s) = o;
      }
    }
  }
}

// ---------------------------------------------------------------------------
// Scores: Sc[b][q][k] = Q[b][q][:].K[b][k][:] (f16 raw), -inf where k > q.
// ---------------------------------------------------------------------------
__global__ __launch_bounds__(256)
void scores_gemm(const _Float16* __restrict__ Q, const _Float16* __restrict__ K,
                 _Float16* __restrict__ Sc) {
  const int tid = threadIdx.x;
  const int bx = blockIdx.x, by = blockIdx.y, bz = blockIdx.z;
  const int n0 = bx * TN, m0 = by * TM;
  _Float16* Cb = Sc + (size_t)bz * 2048 * 2048;

  if (bx > by) {                                 // fully masked tile
    const _Float16 ninf = (_Float16)(-__builtin_inff());
    v8h mv = {ninf, ninf, ninf, ninf, ninf, ninf, ninf, ninf};
#pragma unroll
    for (int it = 0; it < 8; ++it) {
      int ch = it * 256 + tid;
      int r = ch >> 4, cc = (ch & 15) * 8;
      *(v8h*)(Cb + (size_t)(m0 + r) * 2048 + n0 + cc) = mv;
    }
    return;
  }

  __shared__ _Float16 As[TM * BK];
  __shared__ _Float16 Bs[TN * BK];
  const _Float16* Qb = Q + (size_t)bz * 2048 * 1024;
  const _Float16* Kb = K + (size_t)bz * 2048 * 1024;

  const int lane = tid & 63, w = tid >> 6;
  const int wr = (w >> 1) * 64, wc = (w & 1) * 64;
  const int lr = lane & 15, quad = lane >> 4;

  v4f acc[4][4];
#pragma unroll
  for (int i = 0; i < 4; ++i)
#pragma unroll
    for (int j = 0; j < 4; ++j) acc[i][j] = (v4f){0.f, 0.f, 0.f, 0.f};

  for (int kt = 0; kt < 1024 / BK; ++kt) {
    const int k0 = kt * BK;
#pragma unroll
    for (int r = 0; r < 4; ++r) {
      const int c = w * 256 + r * 64 + lane;
      const int row = c >> 3, col = (c & 7) * 8;
      async16(Qb + (size_t)(m0 + row) * 1024 + k0 + col,
              As + (size_t)(w * 256 + r * 64) * 8);
      async16(Kb + (size_t)(n0 + row) * 1024 + k0 + col,
              Bs + (size_t)(w * 256 + r * 64) * 8);
    }
    __syncthreads();
    mfma_slab(As, Bs, wr, wc, lr, quad, acc);
    __syncthreads();
  }

  const _Float16 ninf = (_Float16)(-__builtin_inff());
#pragma unroll
  for (int i = 0; i < 4; ++i) {
    const int r0 = m0 + wr + i * 16 + quad * 4;
#pragma unroll
    for (int j = 0; j < 4; ++j) {
      const int cc = n0 + wc + j * 16 + lr;
#pragma unroll
      for (int rg = 0; rg < 4; ++rg) {
        const int rr = r0 + rg;
        Cb[(size_t)rr * 2048 + cc] = (cc > rr) ? ninf : (_Float16)acc[i][j][rg];
      }
    }
  }
}

// ---------------------------------------------------------------------------
// Row softmax in place (f16), scale 1/32 inside exp.
// ---------------------------------------------------------------------------
__global__ __launch_bounds__(256)
void softmax_rows(_Float16* __restrict__ Sc) {
  _Float16* base = Sc + (size_t)blockIdx.x * 2048;
  const int tid = threadIdx.x;
  const int lane = tid & 63, w = tid >> 6;

  v8h pv = *(const v8h*)(base + tid * 8);
  float f[8];
#pragma unroll
  for (int j = 0; j < 8; ++j) f[j] = (float)pv[j];

  float mx = f[0];
#pragma unroll
  for (int j = 1; j < 8; ++j) mx = fmaxf(mx, f[j]);
#pragma unroll
  for (int off = 32; off; off >>= 1) mx = fmaxf(mx, __shfl_xor(mx, off));
  __shared__ float redm[4], reds[4];
  if (lane == 0) redm[w] = mx;
  __syncthreads();
  mx = fmaxf(fmaxf(redm[0], redm[1]), fmaxf(redm[2], redm[3]));

  const float scale = 0.03125f;                  // 1/sqrt(1024)
  float e[8], s = 0.f;
#pragma unroll
  for (int j = 0; j < 8; ++j) {
    e[j] = __expf((f[j] - mx) * scale);
    s += e[j];
  }
#pragma unroll
  for (int off = 32; off; off >>= 1) s += __shfl_xor(s, off);
  if (lane == 0) reds[w] = s;
  __syncthreads();
  s = reds[0] + reds[1] + reds[2] + reds[3];
  const float inv = 1.0f / s;
#pragma unroll
  for (int j = 0; j < 8; ++j) pv[j] = (_Float16)(e[j] * inv);
  *(v8h*)(base + tid * 8) = pv;
}

// ---------------------------------------------------------------------------
// Out (fp32): out[b][q][d] = sum_k P[b][q][k] * Vt[b][d][k]; K-loop causally
// truncated to (by+1)*128.
// ---------------------------------------------------------------------------
__global__ __launch_bounds__(256)
void pv_gemm(const _Float16* __restrict__ P, const _Float16* __restrict__ Vt,
             float* __restrict__ Out) {
  const int tid = threadIdx.x;
  const int bx = blockIdx.x, by = blockIdx.y, bz = blockIdx.z;
  const int n0 = bx * TN, m0 = by * TM;
  const _Float16* Pb = P + (size_t)bz * 2048 * 2048;
  const _Float16* Vb = Vt + (size_t)bz * 1024 * 2048;
  float* Cb = Out + (size_t)bz * 2048 * 1024;

  __shared__ _Float16 As[TM * BK];
  __shared__ _Float16 Bs[TN * BK];

  const int lane = tid & 63, w = tid >> 6;
  const int wr = (w >> 1) * 64, wc = (w & 1) * 64;
  const int lr = lane & 15, quad = lane >> 4;

  v4f acc[4][4];
#pragma unroll
  for (int i = 0; i < 4; ++i)
#pragma unroll
    for (int j = 0; j < 4; ++j) acc[i][j] = (v4f){0.f, 0.f, 0.f, 0.f};

  const int ksteps = (by + 1) * 2;               // cover k < (by+1)*128
  for (int kt = 0; kt < ksteps; ++kt) {
    const int k0 = kt * BK;
#pragma unroll
    for (int r = 0; r < 4; ++r) {
      const int c = w * 256 + r * 64 + lane;
      const int row = c >> 3, col = (c & 7) * 8;
      async16(Pb + (size_t)(m0 + row) * 2048 + k0 + col,
              As + (size_t)(w * 256 + r * 64) * 8);
      async16(Vb + (size_t)(n0 + row) * 2048 + k0 + col,
              Bs + (size_t)(w * 256 + r * 64) * 8);
    }
    __syncthreads();
    mfma_slab(As, Bs, wr, wc, lr, quad, acc);
    __syncthreads();
  }

#pragma unroll
  for (int i = 0; i < 4; ++i) {
    const int r0 = m0 + wr + i * 16 + quad * 4;
#pragma unroll
    for (int j = 0; j < 4; ++j) {
      const int cc = n0 + wc + j * 16 + lr;
#pragma unroll
      for (int rg = 0; rg < 4; ++rg)
        Cb[(size_t)(r0 + rg) * 1024 + cc] = acc[i][j][rg];   // fp32 store
    }
  }
}

// ---------------------------------------------------------------------------
extern "C" void kernel_launch(void* const* d_in, const int* in_sizes, int n_in,
                              void* d_out, int out_size, void* d_ws, size_t ws_size,
                              hipStream_t stream) {
  const int B = 8, S = 2048, D = 1024;
  const int M = B * S;                           // 16384
  const float* x  = (const float*)d_in[0];
  const float* Wq = (const float*)d_in[1];
  const float* Wk = (const float*)d_in[2];
  const float* Wv = (const float*)d_in[3];
  float* out = (float*)d_out;                    // fp32 output (ref is float32)

  // workspace: Q 32MB | K 32MB | Vt 32MB | Sc 64MB  (160 MB, validated r2)
  char* ws = (char*)d_ws;
  _Float16* Qb = (_Float16*)ws;                          // [M][1024]
  _Float16* Kb = (_Float16*)(ws + (size_t)33554432);     // [M][1024]
  _Float16* Vt = (_Float16*)(ws + (size_t)67108864);     // [B][1024][2048]
  _Float16* Sc = (_Float16*)(ws + (size_t)100663296);    // [B][2048][2048]

  proj_gemm<<<dim3(24, M / TM, 1), 256, 0, stream>>>(x, Wq, Wk, Wv, Qb, Kb, Vt);
  scores_gemm<<<dim3(S / TN, S / TM, B), 256, 0, stream>>>(Qb, Kb, Sc);
  softmax_rows<<<B * S, 256, 0, stream>>>(Sc);
  pv_gemm<<<dim3(D / TN, S / TM, B), 256, 0, stream>>>(Sc, Vt, out);
}

// Round 5
// 476.801 us; speedup vs baseline: 1.1797x; 1.1797x over previous
//
#include <hip/hip_runtime.h>

// ---------------------------------------------------------------------------
// CausalAttention: B=8, S=2048, D=1024, fp32 in, fp32 out.
// Round 5: proj_gemm switched to pure global_load_lds staging (m97 form,
// validated by scores/pv in round 4). fp32->fp16 convert hoisted into a
// memory-bound cvt kernel whose outputs (xh, Wh) alias the Sc region
// (dead before scores writes Sc) -> ws stays 160 MB.
//   ws: Q 32 | K 32 | Vt 32 | Sc 64  (xh@Sc+0 32MB, Wh@Sc+32MB 6MB)
// ---------------------------------------------------------------------------

typedef _Float16 v8h __attribute__((ext_vector_type(8)));
typedef _Float16 v4h __attribute__((ext_vector_type(4)));
typedef float    v4f __attribute__((ext_vector_type(4)));

#define TM 128
#define TN 128
#define BK 64

__device__ __forceinline__ void async16(const _Float16* g, _Float16* l) {
  // global -> LDS direct copy, 16B/lane; LDS dest = wave-uniform base,
  // HW adds lane*16.  [validated r4]
  __builtin_amdgcn_global_load_lds(
      (__attribute__((address_space(1))) void*)(void*)g,
      (__attribute__((address_space(3))) void*)l, 16, 0, 0);
}

// MFMA core over one 128x64 LDS slab pair. A-frag lane: A[m=lane&15][k=quad*8+j].
__device__ __forceinline__ void mfma_slab(const _Float16* As, const _Float16* Bs,
                                          int wr, int wc, int lr, int quad,
                                          v4f acc[4][4]) {
#pragma unroll
  for (int ks = 0; ks < 2; ++ks) {
    v8h a[4], b[4];
#pragma unroll
    for (int i = 0; i < 4; ++i) {
      a[i] = *(const v8h*)&As[(wr + i * 16 + lr) * BK + ks * 32 + quad * 8];
      b[i] = *(const v8h*)&Bs[(wc + i * 16 + lr) * BK + ks * 32 + quad * 8];
    }
#pragma unroll
    for (int i = 0; i < 4; ++i)
#pragma unroll
      for (int j = 0; j < 4; ++j)
        acc[i][j] = __builtin_amdgcn_mfma_f32_16x16x32_f16(a[i], b[j],
                                                           acc[i][j], 0, 0, 0);
  }
}

// ---------------------------------------------------------------------------
// fp32 -> fp16, 8 elems/thread.
// ---------------------------------------------------------------------------
__global__ __launch_bounds__(256)
void cvt_f16(const float* __restrict__ src, _Float16* __restrict__ dst) {
  const int i = (blockIdx.x * 256 + threadIdx.x) * 8;
  float4 a = *(const float4*)(src + i);
  float4 b = *(const float4*)(src + i + 4);
  v8h o = {(_Float16)a.x, (_Float16)a.y, (_Float16)a.z, (_Float16)a.w,
           (_Float16)b.x, (_Float16)b.y, (_Float16)b.z, (_Float16)b.w};
  *(v8h*)(dst + i) = o;
}

// ---------------------------------------------------------------------------
// Projection: C[m][n] = X[m][:] . W[n][:], n in [0,3072) packed Q|K|V,
// all-fp16 glds staging. Q,K stored [16384][1024]; V transposed Vt[b][d][s].
// ---------------------------------------------------------------------------
__global__ __launch_bounds__(256)
void proj_gemm(const _Float16* __restrict__ X, const _Float16* __restrict__ W,
               _Float16* __restrict__ Qb, _Float16* __restrict__ Kb,
               _Float16* __restrict__ Vt) {
  const int tid = threadIdx.x;
  const int n0 = blockIdx.x * TN, m0 = blockIdx.y * TM;
  const int which = n0 >> 10;                    // 0=Q 1=K 2=V, block-uniform
  const int nw = n0 & 1023;

  __shared__ _Float16 As[TM * BK];
  __shared__ _Float16 Bs[TN * BK];

  const int lane = tid & 63, w = tid >> 6;
  const int wr = (w >> 1) * 64, wc = (w & 1) * 64;
  const int lr = lane & 15, quad = lane >> 4;

  v4f acc[4][4];
#pragma unroll
  for (int i = 0; i < 4; ++i)
#pragma unroll
    for (int j = 0; j < 4; ++j) acc[i][j] = (v4f){0.f, 0.f, 0.f, 0.f};

  for (int kt = 0; kt < 1024 / BK; ++kt) {
    const int k0 = kt * BK;
#pragma unroll
    for (int r = 0; r < 4; ++r) {
      const int c = w * 256 + r * 64 + lane;     // chunk id: 8 f16 elems
      const int row = c >> 3, col = (c & 7) * 8;
      async16(X + (size_t)(m0 + row) * 1024 + k0 + col,
              As + (size_t)(w * 256 + r * 64) * 8);
      async16(W + (size_t)(n0 + row) * 1024 + k0 + col,
              Bs + (size_t)(w * 256 + r * 64) * 8);
    }
    __syncthreads();
    mfma_slab(As, Bs, wr, wc, lr, quad, acc);
    __syncthreads();
  }

  // C/D layout: col = lane&15, row = quad*4 + reg  [validated r4]
#pragma unroll
  for (int i = 0; i < 4; ++i) {
    const int r0 = m0 + wr + i * 16 + quad * 4;
#pragma unroll
    for (int j = 0; j < 4; ++j) {
      const int cl = wc + j * 16 + lr;
      if (which < 2) {
        _Float16* dst = (which == 0) ? Qb : Kb;
        const int col = nw + cl;
#pragma unroll
        for (int rg = 0; rg < 4; ++rg)
          dst[(size_t)(r0 + rg) * 1024 + col] = (_Float16)acc[i][j][rg];
      } else {
        const int d = nw + cl;
        const int b = r0 >> 11, s = r0 & 2047;   // 4 rows stay in-batch
        v4h o = {(_Float16)acc[i][j][0], (_Float16)acc[i][j][1],
                 (_Float16)acc[i][j][2], (_Float16)acc[i][j][3]};
        *(v4h*)(Vt + (size_t)b * 1024 * 2048 + (size_t)d * 2048 + s) = o;
      }
    }
  }
}

// ---------------------------------------------------------------------------
// Scores: Sc[b][q][k] = Q[b][q][:].K[b][k][:] (f16 raw), -inf where k > q.
// ---------------------------------------------------------------------------
__global__ __launch_bounds__(256)
void scores_gemm(const _Float16* __restrict__ Q, const _Float16* __restrict__ K,
                 _Float16* __restrict__ Sc) {
  const int tid = threadIdx.x;
  const int bx = blockIdx.x, by = blockIdx.y, bz = blockIdx.z;
  const int n0 = bx * TN, m0 = by * TM;
  _Float16* Cb = Sc + (size_t)bz * 2048 * 2048;

  if (bx > by) {                                 // fully masked tile
    const _Float16 ninf = (_Float16)(-__builtin_inff());
    v8h mv = {ninf, ninf, ninf, ninf, ninf, ninf, ninf, ninf};
#pragma unroll
    for (int it = 0; it < 8; ++it) {
      int ch = it * 256 + tid;
      int r = ch >> 4, cc = (ch & 15) * 8;
      *(v8h*)(Cb + (size_t)(m0 + r) * 2048 + n0 + cc) = mv;
    }
    return;
  }

  __shared__ _Float16 As[TM * BK];
  __shared__ _Float16 Bs[TN * BK];
  const _Float16* Qb = Q + (size_t)bz * 2048 * 1024;
  const _Float16* Kb = K + (size_t)bz * 2048 * 1024;

  const int lane = tid & 63, w = tid >> 6;
  const int wr = (w >> 1) * 64, wc = (w & 1) * 64;
  const int lr = lane & 15, quad = lane >> 4;

  v4f acc[4][4];
#pragma unroll
  for (int i = 0; i < 4; ++i)
#pragma unroll
    for (int j = 0; j < 4; ++j) acc[i][j] = (v4f){0.f, 0.f, 0.f, 0.f};

  for (int kt = 0; kt < 1024 / BK; ++kt) {
    const int k0 = kt * BK;
#pragma unroll
    for (int r = 0; r < 4; ++r) {
      const int c = w * 256 + r * 64 + lane;
      const int row = c >> 3, col = (c & 7) * 8;
      async16(Qb + (size_t)(m0 + row) * 1024 + k0 + col,
              As + (size_t)(w * 256 + r * 64) * 8);
      async16(Kb + (size_t)(n0 + row) * 1024 + k0 + col,
              Bs + (size_t)(w * 256 + r * 64) * 8);
    }
    __syncthreads();
    mfma_slab(As, Bs, wr, wc, lr, quad, acc);
    __syncthreads();
  }

  const _Float16 ninf = (_Float16)(-__builtin_inff());
#pragma unroll
  for (int i = 0; i < 4; ++i) {
    const int r0 = m0 + wr + i * 16 + quad * 4;
#pragma unroll
    for (int j = 0; j < 4; ++j) {
      const int cc = n0 + wc + j * 16 + lr;
#pragma unroll
      for (int rg = 0; rg < 4; ++rg) {
        const int rr = r0 + rg;
        Cb[(size_t)rr * 2048 + cc] = (cc > rr) ? ninf : (_Float16)acc[i][j][rg];
      }
    }
  }
}

// ---------------------------------------------------------------------------
// Row softmax in place (f16), scale 1/32 inside exp.
// ---------------------------------------------------------------------------
__global__ __launch_bounds__(256)
void softmax_rows(_Float16* __restrict__ Sc) {
  _Float16* base = Sc + (size_t)blockIdx.x * 2048;
  const int tid = threadIdx.x;
  const int lane = tid & 63, w = tid >> 6;

  v8h pv = *(const v8h*)(base + tid * 8);
  float f[8];
#pragma unroll
  for (int j = 0; j < 8; ++j) f[j] = (float)pv[j];

  float mx = f[0];
#pragma unroll
  for (int j = 1; j < 8; ++j) mx = fmaxf(mx, f[j]);
#pragma unroll
  for (int off = 32; off; off >>= 1) mx = fmaxf(mx, __shfl_xor(mx, off));
  __shared__ float redm[4], reds[4];
  if (lane == 0) redm[w] = mx;
  __syncthreads();
  mx = fmaxf(fmaxf(redm[0], redm[1]), fmaxf(redm[2], redm[3]));

  const float scale = 0.03125f;                  // 1/sqrt(1024)
  float e[8], s = 0.f;
#pragma unroll
  for (int j = 0; j < 8; ++j) {
    e[j] = __expf((f[j] - mx) * scale);
    s += e[j];
  }
#pragma unroll
  for (int off = 32; off; off >>= 1) s += __shfl_xor(s, off);
  if (lane == 0) reds[w] = s;
  __syncthreads();
  s = reds[0] + reds[1] + reds[2] + reds[3];
  const float inv = 1.0f / s;
#pragma unroll
  for (int j = 0; j < 8; ++j) pv[j] = (_Float16)(e[j] * inv);
  *(v8h*)(base + tid * 8) = pv;
}

// ---------------------------------------------------------------------------
// Out (fp32): out[b][q][d] = sum_k P[b][q][k] * Vt[b][d][k]; K-loop causally
// truncated to (by+1)*128.
// ---------------------------------------------------------------------------
__global__ __launch_bounds__(256)
void pv_gemm(const _Float16* __restrict__ P, const _Float16* __restrict__ Vt,
             float* __restrict__ Out) {
  const int tid = threadIdx.x;
  const int bx = blockIdx.x, by = blockIdx.y, bz = blockIdx.z;
  const int n0 = bx * TN, m0 = by * TM;
  const _Float16* Pb = P + (size_t)bz * 2048 * 2048;
  const _Float16* Vb = Vt + (size_t)bz * 1024 * 2048;
  float* Cb = Out + (size_t)bz * 2048 * 1024;

  __shared__ _Float16 As[TM * BK];
  __shared__ _Float16 Bs[TN * BK];

  const int lane = tid & 63, w = tid >> 6;
  const int wr = (w >> 1) * 64, wc = (w & 1) * 64;
  const int lr = lane & 15, quad = lane >> 4;

  v4f acc[4][4];
#pragma unroll
  for (int i = 0; i < 4; ++i)
#pragma unroll
    for (int j = 0; j < 4; ++j) acc[i][j] = (v4f){0.f, 0.f, 0.f, 0.f};

  const int ksteps = (by + 1) * 2;               // cover k < (by+1)*128
  for (int kt = 0; kt < ksteps; ++kt) {
    const int k0 = kt * BK;
#pragma unroll
    for (int r = 0; r < 4; ++r) {
      const int c = w * 256 + r * 64 + lane;
      const int row = c >> 3, col = (c & 7) * 8;
      async16(Pb + (size_t)(m0 + row) * 2048 + k0 + col,
              As + (size_t)(w * 256 + r * 64) * 8);
      async16(Vb + (size_t)(n0 + row) * 2048 + k0 + col,
              Bs + (size_t)(w * 256 + r * 64) * 8);
    }
    __syncthreads();
    mfma_slab(As, Bs, wr, wc, lr, quad, acc);
    __syncthreads();
  }

#pragma unroll
  for (int i = 0; i < 4; ++i) {
    const int r0 = m0 + wr + i * 16 + quad * 4;
#pragma unroll
    for (int j = 0; j < 4; ++j) {
      const int cc = n0 + wc + j * 16 + lr;
#pragma unroll
      for (int rg = 0; rg < 4; ++rg)
        Cb[(size_t)(r0 + rg) * 1024 + cc] = acc[i][j][rg];   // fp32 store
    }
  }
}

// ---------------------------------------------------------------------------
extern "C" void kernel_launch(void* const* d_in, const int* in_sizes, int n_in,
                              void* d_out, int out_size, void* d_ws, size_t ws_size,
                              hipStream_t stream) {
  const int B = 8, S = 2048, D = 1024;
  const int M = B * S;                           // 16384
  const float* x  = (const float*)d_in[0];
  const float* Wq = (const float*)d_in[1];
  const float* Wk = (const float*)d_in[2];
  const float* Wv = (const float*)d_in[3];
  float* out = (float*)d_out;

  // ws: Q 32MB | K 32MB | Vt 32MB | Sc 64MB (160 MB total, validated r4).
  // xh (32MB) and Wh (6MB) alias the head of Sc — dead before scores writes.
  char* ws = (char*)d_ws;
  _Float16* Qb = (_Float16*)ws;                          // [M][1024]
  _Float16* Kb = (_Float16*)(ws + (size_t)33554432);     // [M][1024]
  _Float16* Vt = (_Float16*)(ws + (size_t)67108864);     // [B][1024][2048]
  _Float16* Sc = (_Float16*)(ws + (size_t)100663296);    // [B][2048][2048]
  _Float16* xh = Sc;                                     // [M][1024]   (alias)
  _Float16* Wh = Sc + (size_t)M * D;                     // [3072][1024](alias)

  // 1) fp32 -> fp16 converts (memory-bound)
  cvt_f16<<<(M * D) / 2048, 256, 0, stream>>>(x, xh);
  cvt_f16<<<(D * D) / 2048, 256, 0, stream>>>(Wq, Wh);
  cvt_f16<<<(D * D) / 2048, 256, 0, stream>>>(Wk, Wh + (size_t)D * D);
  cvt_f16<<<(D * D) / 2048, 256, 0, stream>>>(Wv, Wh + (size_t)2 * D * D);

  // 2) QKV projection (pure glds GEMM)
  proj_gemm<<<dim3(24, M / TM, 1), 256, 0, stream>>>(xh, Wh, Qb, Kb, Vt);

  // 3) raw scores with causal -inf mask
  scores_gemm<<<dim3(S / TN, S / TM, B), 256, 0, stream>>>(Qb, Kb, Sc);

  // 4) softmax rows in place
  softmax_rows<<<B * S, 256, 0, stream>>>(Sc);

  // 5) out = P @ Vt, fp32 store
  pv_gemm<<<dim3(D / TN, S / TM, B), 256, 0, stream>>>(Sc, Vt, out);
}